// Round 11
// baseline (365.235 us; speedup 1.0000x reference)
//
#include <hip/hip_runtime.h>

#define N_NODES 100000
#define N_EDGES 3200000
#define D 64
#define EPS 1e-5f

#define BSHIFT 7
#define BNODES 128                                          // nodes per bucket
#define NBUCK ((N_NODES + BNODES - 1) / BNODES)             // 782
#define P1_CHUNK 8192
#define NB_P1 ((N_EDGES + P1_CHUNK - 1) / P1_CHUNK)         // 391
#define SRC_MASK 0x1FFFFu                                   // 17 bits >= 100000
#define RAWCAP 4480                                         // per-bucket edge cap (mean 4092)
#define BCAP 5120                                           // padded region cap (RAWCAP + 128*3, rounded)
#define TBL_STRIDE 784                                      // 783 entries + pad
#define SENT N_NODES                                        // sentinel -> zero row
#define NWAVE (N_NODES / 8)                                 // 12500 agg waves

typedef __attribute__((ext_vector_type(8))) short bf16x8;   // 8 bf16 = 4 VGPRs
typedef __attribute__((ext_vector_type(4))) float f32x4;

__device__ __forceinline__ unsigned short f2bf(float f) {
  unsigned int u = __float_as_uint(f);
  u += 0x7FFFu + ((u >> 16) & 1u);          // round to nearest even
  return (unsigned short)(u >> 16);
}
__device__ __forceinline__ float bf2f(unsigned short h) {
  return __uint_as_float(((unsigned int)h) << 16);
}
__device__ __forceinline__ float2 bfpair(unsigned int u) {
  return make_float2(__uint_as_float(u << 16), __uint_as_float(u & 0xFFFF0000u));
}
// add 8 bf16 (packed in uint4) into 4 float2 accumulators (pairs -> v_pk_add)
__device__ __forceinline__ void addp(float2 a[4], uint4 u) {
  a[0] += bfpair(u.x);
  a[1] += bfpair(u.y);
  a[2] += bfpair(u.z);
  a[3] += bfpair(u.w);
}

// ---------------------------------------------------------------------------
// blocks 0,1: fold GCNConv+FC into 64x64, emit MFMA-B-swizzled bf16 + bc.
// block 2: zero BN stat accumulators + the sentinel (zero) feature row.
// ---------------------------------------------------------------------------
__global__ __launch_bounds__(256) void combine_weights(
    const float* __restrict__ W1, const float* __restrict__ b1,
    const float* __restrict__ fw1, const float* __restrict__ fb1,
    const float* __restrict__ W2, const float* __restrict__ b2,
    const float* __restrict__ fw2, const float* __restrict__ fb2,
    unsigned int* __restrict__ WcB1, float* __restrict__ bc1,
    unsigned int* __restrict__ WcB2, float* __restrict__ bc2,
    float* __restrict__ stats, unsigned short* __restrict__ Xs) {
  if (blockIdx.x == 2) {
    if (threadIdx.x < 256) stats[threadIdx.x] = 0.0f;
    if (threadIdx.x < 64) Xs[(size_t)N_NODES * D + threadIdx.x] = 0;  // zero row
    return;
  }
  const float* W  = blockIdx.x ? W2  : W1;
  const float* fw = blockIdx.x ? fw2 : fw1;
  const float* b  = blockIdx.x ? b2  : b1;
  const float* fb = blockIdx.x ? fb2 : fb1;
  unsigned int* WcB = blockIdx.x ? WcB2 : WcB1;
  float* bc = blockIdx.x ? bc2 : bc1;

  __shared__ float sW[64 * 64];
  __shared__ float sf[64 * 64];
  __shared__ float sC[64 * 64];
  for (int i = threadIdx.x; i < 4096; i += 256) { sW[i] = W[i]; sf[i] = fw[i]; }
  __syncthreads();
  for (int o = threadIdx.x; o < 4096; o += 256) {
    int i = o >> 6, j = o & 63;
    float acc = 0.f;
    #pragma unroll
    for (int k = 0; k < 64; ++k) acc += sW[i * 64 + k] * sf[k * 64 + j];
    sC[o] = acc;
  }
  __syncthreads();
  // B-fragment swizzle: frag f=(nt*2+kh), lane L, elem j -> B[(L>>4)*8+j+kh*32][nt*16+(L&15)]
  for (int o = threadIdx.x; o < 2048; o += 256) {
    int jj = o & 3, L = (o >> 2) & 63, kh = (o >> 8) & 1, nt = o >> 9;
    int k0 = (L >> 4) * 8 + jj * 2 + kh * 32;
    int n  = nt * 16 + (L & 15);
    unsigned int lo = f2bf(sC[k0 * 64 + n]);
    unsigned int hi = f2bf(sC[(k0 + 1) * 64 + n]);
    WcB[o] = (hi << 16) | lo;
  }
  if (threadIdx.x < 64) {
    int j = threadIdx.x;
    float acc = fb[j];
    #pragma unroll
    for (int k = 0; k < 64; ++k) acc += b[k] * sf[k * 64 + j];
    bc[j] = acc;
  }
}

// ---------------------------------------------------------------------------
// Pass 1: block-local counting sort of an 8192-edge chunk by 128-node bucket.
// ---------------------------------------------------------------------------
__global__ __launch_bounds__(512) void pass1_sort(
    const int* __restrict__ src, const int* __restrict__ dst,
    unsigned int* __restrict__ stage, unsigned short* __restrict__ tbl) {
  __shared__ unsigned int hist[NBUCK];
  __shared__ unsigned int ts[512];
  __shared__ unsigned int sorted[P1_CHUNK];
  const int tid = threadIdx.x;
  const int e0 = blockIdx.x * P1_CHUNK;

  for (int b = tid; b < NBUCK; b += 512) hist[b] = 0;
  __syncthreads();

  int dreg[16];
  #pragma unroll
  for (int k = 0; k < 16; ++k) {
    int e = e0 + k * 512 + tid;
    int d = (e < N_EDGES) ? dst[e] : -1;
    dreg[k] = d;
    if (d >= 0) atomicAdd(&hist[((unsigned)d) >> BSHIFT], 1u);
  }
  __syncthreads();

  unsigned int v0 = (2 * tid < NBUCK) ? hist[2 * tid] : 0u;
  unsigned int v1 = (2 * tid + 1 < NBUCK) ? hist[2 * tid + 1] : 0u;
  unsigned int run = v0 + v1;
  ts[tid] = run;
  __syncthreads();
  for (int o = 1; o < 512; o <<= 1) {
    unsigned int add = (tid >= o) ? ts[tid - o] : 0u;
    __syncthreads();
    ts[tid] += add;
    __syncthreads();
  }
  const unsigned int excl = ts[tid] - run;
  const unsigned int m = ts[511];
  unsigned short* trow = tbl + (size_t)blockIdx.x * TBL_STRIDE;
  if (2 * tid < NBUCK)     { hist[2 * tid]     = excl;      trow[2 * tid]     = (unsigned short)excl; }
  if (2 * tid + 1 < NBUCK) { hist[2 * tid + 1] = excl + v0; trow[2 * tid + 1] = (unsigned short)(excl + v0); }
  if (tid == 0) trow[NBUCK] = (unsigned short)m;
  __syncthreads();

  #pragma unroll
  for (int k = 0; k < 16; ++k) {
    int e = e0 + k * 512 + tid;
    int t = dreg[k];
    if (t >= 0) {
      unsigned int pos = atomicAdd(&hist[((unsigned)t) >> BSHIFT], 1u);
      sorted[pos] = (((unsigned)(t & (BNODES - 1))) << 17) | (unsigned)src[e];
    }
  }
  __syncthreads();

  unsigned int* so = stage + (size_t)blockIdx.x * P1_CHUNK;
  for (int i = tid; i < (int)m; i += 512) so[i] = sorted[i];
}

// ---------------------------------------------------------------------------
// Pass 2: lane-per-segment gather -> LDS counting sort to node CSR with each
// node's list padded to a multiple of 4 using SENT (zero-row index).
// Emits eSrc (padded, 4-aligned per node), off, pq=(pad4(deg)/4), wmax (max pq
// per 8-node wave group), dinv, and the fused layer-1 prescale Xs.
// ---------------------------------------------------------------------------
__global__ __launch_bounds__(512) void pass2_sort(
    const unsigned int* __restrict__ stage, const unsigned short* __restrict__ tbl,
    int* __restrict__ eSrc, int* __restrict__ off, int* __restrict__ pq,
    int* __restrict__ wmax, float* __restrict__ dinv,
    const float* __restrict__ x, unsigned short* __restrict__ Xs) {
  __shared__ int segbase[NB_P1];
  __shared__ int spre[512];
  __shared__ int cnt[BNODES];
  __shared__ int pqs[BNODES];
  __shared__ int ts[BNODES];
  __shared__ float dinvL[BNODES];
  __shared__ unsigned int raw[RAWCAP];
  __shared__ int sorted[BCAP];
  const int b = blockIdx.x, tid = threadIdx.x;
  const int n0 = b * BNODES;

  int len = 0;
  if (tid < NB_P1) {
    const unsigned short* trow = tbl + (size_t)tid * TBL_STRIDE;
    int o0 = trow[b], o1 = trow[b + 1];
    segbase[tid] = tid * P1_CHUNK + o0;
    len = o1 - o0;
  }
  if (tid < BNODES) cnt[tid] = 0;
  spre[tid] = len;
  __syncthreads();
  for (int o = 1; o < 512; o <<= 1) {
    int add = (tid >= o) ? spre[tid - o] : 0;
    __syncthreads();
    spre[tid] += add;
    __syncthreads();
  }
  const int m = spre[511];
  const int pref = spre[tid] - len;

  if (tid < NB_P1) {
    const int base = segbase[tid];
    for (int j = 0; j < len; ++j) {
      unsigned int p = stage[base + j];
      raw[pref + j] = p;
      atomicAdd(&cnt[p >> 17], 1);
    }
  }
  __syncthreads();

  // padded scan: pc = pad4(deg)
  int v = 0, pc = 0;
  if (tid < BNODES) { v = cnt[tid]; pc = (v + 3) & ~3; ts[tid] = pc; }
  __syncthreads();
  for (int o = 1; o < BNODES; o <<= 1) {
    int add = (tid >= o && tid < BNODES) ? ts[tid - o] : 0;
    __syncthreads();
    if (tid < BNODES) ts[tid] += add;
    __syncthreads();
  }
  const int mp = ts[BNODES - 1];              // padded total (<= BCAP)
  if (tid < BNODES) {
    int excl = ts[tid] - pc;
    int node = n0 + tid;
    float dv = rsqrtf((float)v + 1.0f);
    dinvL[tid] = dv;
    pqs[tid] = pc >> 2;
    if (node < N_NODES) {
      off[node] = b * BCAP + excl;
      pq[node]  = pc >> 2;
      dinv[node] = dv;
    }
    cnt[tid] = excl;                          // becomes cursor
  }
  __syncthreads();
  if (tid < BNODES / 8) {                     // wmax per 8-node wave group
    int mx = 0;
    #pragma unroll
    for (int k = 0; k < 8; ++k) mx = max(mx, pqs[tid * 8 + k]);
    int n8 = n0 + tid * 8;
    if (n8 < N_NODES) wmax[n8 >> 3] = mx;
  }
  for (int i = tid; i < mp; i += 512) sorted[i] = SENT;  // padding slots
  __syncthreads();

  for (int i = tid; i < m; i += 512) {
    unsigned int p = raw[i];
    int pos = atomicAdd(&cnt[p >> 17], 1);
    sorted[pos] = (int)(p & SRC_MASK);
  }
  __syncthreads();

  int* out = eSrc + (size_t)b * BCAP;
  for (int i = tid; i < mp; i += 512) out[i] = sorted[i];

  // fused layer-1 prescale for this block's node range
  const int rows = min(BNODES, N_NODES - n0);
  for (int i = tid; i < rows * 64; i += 512) {
    int r = i >> 6;
    size_t g = (size_t)(n0 + r) * 64 + (i & 63);
    Xs[g] = f2bf(dinvL[r] * x[g]);
  }
}

// ---------------------------------------------------------------------------
// CSR aggregation v4: 8 nodes per wave (grp = node, sub = 16B chunk).
// Per iteration: one int4 edge-id load (4 edges/node) + 4 row gathers.
// No cross-lane epilogue; sentinel zero-row handles padding; cndmask handles
// iterations past a node's own quad count.
// ---------------------------------------------------------------------------
__global__ __launch_bounds__(256) void agg_csr(
    const int* __restrict__ off, const int* __restrict__ pq,
    const int* __restrict__ wmax, const int* __restrict__ eSrc,
    const unsigned short* __restrict__ Xs, const float* __restrict__ dinv,
    unsigned short* __restrict__ agg) {
  const int wid = (blockIdx.x * 256 + threadIdx.x) >> 6;   // 0..NWAVE-1
  const int lane = threadIdx.x & 63;
  const int g = lane >> 3, sub = lane & 7;
  const int n = wid * 8 + g;                               // < N_NODES always
  const uint4* XsV = (const uint4*)Xs;

  const int o = off[n];
  const int q = pq[n];
  const int wq = wmax[wid];
  const float dv = dinv[n];

  uint4 u0 = XsV[(size_t)n * 8 + sub];        // self loop
  float2 acc[4];
  acc[0] = bfpair(u0.x);
  acc[1] = bfpair(u0.y);
  acc[2] = bfpair(u0.z);
  acc[3] = bfpair(u0.w);

  const int4* E = (const int4*)(eSrc + o);    // o is 4-aligned
  for (int it = 0; it < wq; ++it) {
    int4 idx = E[it];
    if (it >= q) { idx.x = SENT; idx.y = SENT; idx.z = SENT; idx.w = SENT; }
    uint4 ua = XsV[(size_t)idx.x * 8 + sub];
    uint4 ub = XsV[(size_t)idx.y * 8 + sub];
    uint4 uc = XsV[(size_t)idx.z * 8 + sub];
    uint4 ud = XsV[(size_t)idx.w * 8 + sub];
    addp(acc, ua); addp(acc, ub); addp(acc, uc); addp(acc, ud);
  }

  uint4 o4;
  o4.x = ((unsigned)f2bf(acc[0].y * dv) << 16) | f2bf(acc[0].x * dv);
  o4.y = ((unsigned)f2bf(acc[1].y * dv) << 16) | f2bf(acc[1].x * dv);
  o4.z = ((unsigned)f2bf(acc[2].y * dv) << 16) | f2bf(acc[2].x * dv);
  o4.w = ((unsigned)f2bf(acc[3].y * dv) << 16) | f2bf(acc[3].x * dv);
  *(uint4*)(agg + (size_t)n * 64 + sub * 8) = o4;
}

// ---------------------------------------------------------------------------
// MFMA GEMM: Yb(bf16)[128-row block] = A(bf16) @ WcB + bc, fused col stats.
// ---------------------------------------------------------------------------
__global__ __launch_bounds__(256) void gemm_stats(
    const unsigned short* __restrict__ A, const unsigned int* __restrict__ WcB,
    const float* __restrict__ bc, unsigned short* __restrict__ Yb,
    float* __restrict__ colsum, float* __restrict__ colsq) {
  const int tid = threadIdx.x;
  const int L = tid & 63, wv = tid >> 6;
  const int quad = L >> 4, l16 = L & 15;

  const bf16x8* Wv = (const bf16x8*)WcB;
  bf16x8 bfr[4][2];
  #pragma unroll
  for (int nt = 0; nt < 4; ++nt)
    #pragma unroll
    for (int kh = 0; kh < 2; ++kh)
      bfr[nt][kh] = Wv[(nt * 2 + kh) * 64 + L];
  float bcv[4];
  #pragma unroll
  for (int nt = 0; nt < 4; ++nt) bcv[nt] = bc[nt * 16 + l16];

  const bf16x8* Av = (const bf16x8*)A;
  float psum[4] = {0.f, 0.f, 0.f, 0.f}, psq[4] = {0.f, 0.f, 0.f, 0.f};

  #pragma unroll
  for (int loop = 0; loop < 2; ++loop) {
    const int rowbase = blockIdx.x * 128 + loop * 64 + wv * 16;
    const int m = min(rowbase + l16, N_NODES - 1);
    bf16x8 a0 = Av[(size_t)m * 8 + quad];
    bf16x8 a1 = Av[(size_t)m * 8 + 4 + quad];
    #pragma unroll
    for (int nt = 0; nt < 4; ++nt) {
      f32x4 acc = {0.f, 0.f, 0.f, 0.f};
      acc = __builtin_amdgcn_mfma_f32_16x16x32_bf16(a0, bfr[nt][0], acc, 0, 0, 0);
      acc = __builtin_amdgcn_mfma_f32_16x16x32_bf16(a1, bfr[nt][1], acc, 0, 0, 0);
      #pragma unroll
      for (int r = 0; r < 4; ++r) {
        int row = rowbase + quad * 4 + r;
        if (row < N_NODES) {
          float y = acc[r] + bcv[nt];
          Yb[(size_t)row * 64 + nt * 16 + l16] = f2bf(y);
          psum[nt] += y;
          psq[nt] += y * y;
        }
      }
    }
  }

  #pragma unroll
  for (int nt = 0; nt < 4; ++nt) {
    psum[nt] += __shfl_xor(psum[nt], 16, 64);
    psum[nt] += __shfl_xor(psum[nt], 32, 64);
    psq[nt]  += __shfl_xor(psq[nt], 16, 64);
    psq[nt]  += __shfl_xor(psq[nt], 32, 64);
  }
  __shared__ float rsum[4][64];
  __shared__ float rsq[4][64];
  if (L < 16) {
    #pragma unroll
    for (int nt = 0; nt < 4; ++nt) {
      rsum[wv][nt * 16 + L] = psum[nt];
      rsq[wv][nt * 16 + L]  = psq[nt];
    }
  }
  __syncthreads();
  if (tid < 64) {
    float s = rsum[0][tid] + rsum[1][tid] + rsum[2][tid] + rsum[3][tid];
    float q = rsq[0][tid] + rsq[1][tid] + rsq[2][tid] + rsq[3][tid];
    atomicAdd(&colsum[tid], s);
    atomicAdd(&colsq[tid], q);
  }
}

// ---------------------------------------------------------------------------
// prescale_y (+inline finalize of layer-1 BN), in place over the Yb buffer
// ---------------------------------------------------------------------------
__global__ __launch_bounds__(256) void prescale_y(
    unsigned short* __restrict__ YbXs, const float* __restrict__ dinv,
    const float* __restrict__ colsum, const float* __restrict__ colsq,
    const float* __restrict__ g, const float* __restrict__ bt) {
  __shared__ float sa[64], sc[64];
  if (threadIdx.x < 64) {
    int j = threadIdx.x;
    float mu = colsum[j] * (1.0f / N_NODES);
    float var = colsq[j] * (1.0f / N_NODES) - mu * mu;
    float s = rsqrtf(var + EPS) * g[j];
    sa[j] = s;
    sc[j] = bt[j] - mu * s;
  }
  __syncthreads();
  int idx = blockIdx.x * blockDim.x + threadIdx.x;
  if (idx < N_NODES * D) {
    int i = idx >> 6, j = idx & 63;
    float y = bf2f(YbXs[idx]);
    YbXs[idx] = f2bf(dinv[i] * fmaxf(fmaf(y, sa[j], sc[j]), 0.f));
  }
}

// ---------------------------------------------------------------------------
// final_norm (+inline finalize of layer-2 BN): out = relu(Yb*a2 + c2), fp32
// ---------------------------------------------------------------------------
__global__ __launch_bounds__(256) void final_norm(
    const unsigned short* __restrict__ Yb, float* __restrict__ out,
    const float* __restrict__ colsum, const float* __restrict__ colsq,
    const float* __restrict__ g, const float* __restrict__ bt) {
  __shared__ float sa[64], sc[64];
  if (threadIdx.x < 64) {
    int j = threadIdx.x;
    float mu = colsum[j] * (1.0f / N_NODES);
    float var = colsq[j] * (1.0f / N_NODES) - mu * mu;
    float s = rsqrtf(var + EPS) * g[j];
    sa[j] = s;
    sc[j] = bt[j] - mu * s;
  }
  __syncthreads();
  int idx = blockIdx.x * blockDim.x + threadIdx.x;
  if (idx < N_NODES * D) {
    int j = idx & 63;
    out[idx] = fmaxf(fmaf(bf2f(Yb[idx]), sa[j], sc[j]), 0.f);
  }
}

extern "C" void kernel_launch(void* const* d_in, const int* in_sizes, int n_in,
                              void* d_out, int out_size, void* d_ws, size_t ws_size,
                              hipStream_t stream) {
  const float* x   = (const float*)d_in[0];
  const int*   src = (const int*)d_in[1];          // edge_index row 0
  const int*   dst = src + N_EDGES;                // edge_index row 1
  const float* W1  = (const float*)d_in[2];
  const float* b1  = (const float*)d_in[3];
  const float* fw1 = (const float*)d_in[4];
  const float* fb1 = (const float*)d_in[5];
  const float* g1  = (const float*)d_in[6];
  const float* bt1 = (const float*)d_in[7];
  const float* W2  = (const float*)d_in[8];
  const float* b2  = (const float*)d_in[9];
  const float* fw2 = (const float*)d_in[10];
  const float* fb2 = (const float*)d_in[11];
  const float* g2  = (const float*)d_in[12];
  const float* bt2 = (const float*)d_in[13];

  float* out = (float*)d_out;                      // N x 64 fp32

  // workspace (~46 MB). stage aliases aggb; XsYb has N+1 rows (row N = zeros,
  // the sentinel row). XsYb doubles as the bf16 Y buffer between stages.
  unsigned char* w = (unsigned char*)d_ws;
  unsigned int*   stage = (unsigned int*)w;              // NB_P1*8192 uints
  unsigned short* aggb  = (unsigned short*)w;            // N*64 bf16 (alias)
  size_t ofs = ((size_t)NB_P1 * P1_CHUNK * 4 + 255) & ~(size_t)255;
  float*          dinv  = (float*)(w + ofs);             // N floats
  unsigned short* XsYb  = (unsigned short*)(dinv + N_NODES);          // (N+1)*64 bf16
  int*            eSrc  = (int*)(XsYb + (size_t)(N_NODES + 8) * D);   // NBUCK*BCAP + slack
  int*            off   = eSrc + (size_t)NBUCK * BCAP + 1024;         // N ints
  int*            pq    = off + N_NODES;                 // N ints
  int*            wmax  = pq + N_NODES;                  // NWAVE ints
  unsigned short* tbl   = (unsigned short*)(wmax + NWAVE);            // NB_P1*784 ushort
  unsigned int* WcB1 = (unsigned int*)(tbl + (size_t)NB_P1 * TBL_STRIDE); // 2048
  float* bc1  = (float*)(WcB1 + 2048);             // 64
  unsigned int* WcB2 = (unsigned int*)(bc1 + 64);  // 2048
  float* bc2  = (float*)(WcB2 + 2048);             // 64
  float* sum1 = bc2 + 64;                          // 64  (sum1..sq2 contiguous 256)
  float* sq1  = sum1 + 64;
  float* sum2 = sq1 + 64;
  float* sq2  = sum2 + 64;

  const int nd = N_NODES * D;
  dim3 blk(256);

  combine_weights<<<3, blk, 0, stream>>>(W1, b1, fw1, fb1, W2, b2, fw2, fb2,
                                         WcB1, bc1, WcB2, bc2, sum1, XsYb);

  // ---- partition: block-local sort -> padded per-bucket node CSR ----
  pass1_sort<<<NB_P1, 512, 0, stream>>>(src, dst, stage, tbl);
  pass2_sort<<<NBUCK, 512, 0, stream>>>(stage, tbl, eSrc, off, pq, wmax, dinv, x, XsYb);

  // ---- layer 1 ----
  agg_csr<<<NWAVE / 4, blk, 0, stream>>>(off, pq, wmax, eSrc, XsYb, dinv, aggb);
  gemm_stats<<<(N_NODES + 127) / 128, blk, 0, stream>>>(aggb, WcB1, bc1, XsYb, sum1, sq1);

  // ---- layer 2 ----
  prescale_y<<<(nd + 255) / 256, blk, 0, stream>>>(XsYb, dinv, sum1, sq1, g1, bt1);
  agg_csr<<<NWAVE / 4, blk, 0, stream>>>(off, pq, wmax, eSrc, XsYb, dinv, aggb);
  gemm_stats<<<(N_NODES + 127) / 128, blk, 0, stream>>>(aggb, WcB2, bc2, XsYb, sum2, sq2);

  final_norm<<<(nd + 255) / 256, blk, 0, stream>>>(XsYb, out, sum2, sq2, g2, bt2);
}

// Round 12
// 342.493 us; speedup vs baseline: 1.0664x; 1.0664x over previous
//
#include <hip/hip_runtime.h>

#define N_NODES 100000
#define N_EDGES 3200000
#define D 64
#define EPS 1e-5f

#define BSHIFT 7
#define BNODES 128                                          // nodes per bucket
#define NBUCK ((N_NODES + BNODES - 1) / BNODES)             // 782
#define P1_CHUNK 4096
#define NB_P1 ((N_EDGES + P1_CHUNK - 1) / P1_CHUNK)         // 782
#define SRC_MASK 0x1FFFFu                                   // 17 bits >= 100000
#define BCAP 4480                                           // bucket region cap
#define TBL_STRIDE 784                                      // 783 entries + pad

typedef __attribute__((ext_vector_type(8))) short bf16x8;   // 8 bf16 = 4 VGPRs
typedef __attribute__((ext_vector_type(4))) float f32x4;

__device__ __forceinline__ unsigned short f2bf(float f) {
  unsigned int u = __float_as_uint(f);
  u += 0x7FFFu + ((u >> 16) & 1u);          // round to nearest even
  return (unsigned short)(u >> 16);
}
__device__ __forceinline__ float bf2f(unsigned short h) {
  return __uint_as_float(((unsigned int)h) << 16);
}
__device__ __forceinline__ float2 bfpair(unsigned int u) {
  return make_float2(__uint_as_float(u << 16), __uint_as_float(u & 0xFFFF0000u));
}
// add 8 bf16 (packed in uint4) into 4 float2 accumulators (pairs -> v_pk_add)
__device__ __forceinline__ void addp(float2 a[4], uint4 u) {
  a[0] += bfpair(u.x);
  a[1] += bfpair(u.y);
  a[2] += bfpair(u.z);
  a[3] += bfpair(u.w);
}

// ---------------------------------------------------------------------------
// blocks 0,1: fold GCNConv+FC into 64x64, emit MFMA-B-swizzled bf16 + bc.
// block 2: zero BN stat accumulators.
// ---------------------------------------------------------------------------
__global__ __launch_bounds__(256) void combine_weights(
    const float* __restrict__ W1, const float* __restrict__ b1,
    const float* __restrict__ fw1, const float* __restrict__ fb1,
    const float* __restrict__ W2, const float* __restrict__ b2,
    const float* __restrict__ fw2, const float* __restrict__ fb2,
    unsigned int* __restrict__ WcB1, float* __restrict__ bc1,
    unsigned int* __restrict__ WcB2, float* __restrict__ bc2,
    float* __restrict__ stats) {
  if (blockIdx.x == 2) {
    if (threadIdx.x < 256) stats[threadIdx.x] = 0.0f;
    return;
  }
  const float* W  = blockIdx.x ? W2  : W1;
  const float* fw = blockIdx.x ? fw2 : fw1;
  const float* b  = blockIdx.x ? b2  : b1;
  const float* fb = blockIdx.x ? fb2 : fb1;
  unsigned int* WcB = blockIdx.x ? WcB2 : WcB1;
  float* bc = blockIdx.x ? bc2 : bc1;

  __shared__ float sW[64 * 64];
  __shared__ float sf[64 * 64];
  __shared__ float sC[64 * 64];
  for (int i = threadIdx.x; i < 4096; i += 256) { sW[i] = W[i]; sf[i] = fw[i]; }
  __syncthreads();
  for (int o = threadIdx.x; o < 4096; o += 256) {
    int i = o >> 6, j = o & 63;
    float acc = 0.f;
    #pragma unroll
    for (int k = 0; k < 64; ++k) acc += sW[i * 64 + k] * sf[k * 64 + j];
    sC[o] = acc;
  }
  __syncthreads();
  // B-fragment swizzle: frag f=(nt*2+kh), lane L, elem j -> B[(L>>4)*8+j+kh*32][nt*16+(L&15)]
  for (int o = threadIdx.x; o < 2048; o += 256) {
    int jj = o & 3, L = (o >> 2) & 63, kh = (o >> 8) & 1, nt = o >> 9;
    int k0 = (L >> 4) * 8 + jj * 2 + kh * 32;
    int n  = nt * 16 + (L & 15);
    unsigned int lo = f2bf(sC[k0 * 64 + n]);
    unsigned int hi = f2bf(sC[(k0 + 1) * 64 + n]);
    WcB[o] = (hi << 16) | lo;
  }
  if (threadIdx.x < 64) {
    int j = threadIdx.x;
    float acc = fb[j];
    #pragma unroll
    for (int k = 0; k < 64; ++k) acc += b[k] * sf[k * 64 + j];
    bc[j] = acc;
  }
}

// ---------------------------------------------------------------------------
// Pass 1: block-local counting sort of a 4096-edge chunk by 128-node bucket.
// 782 blocks x 256 threads (~3 resident blocks/CU for latency overlap).
// ---------------------------------------------------------------------------
__global__ __launch_bounds__(256) void pass1_sort(
    const int* __restrict__ src, const int* __restrict__ dst,
    unsigned int* __restrict__ stage, unsigned short* __restrict__ tbl) {
  __shared__ unsigned int hist[NBUCK];
  __shared__ unsigned int ts[256];
  __shared__ unsigned int sorted[P1_CHUNK];
  const int tid = threadIdx.x;
  const int e0 = blockIdx.x * P1_CHUNK;

  for (int b = tid; b < NBUCK; b += 256) hist[b] = 0;
  __syncthreads();

  int dreg[16];                               // dst cached -> no second dst read
  #pragma unroll
  for (int k = 0; k < 16; ++k) {
    int e = e0 + k * 256 + tid;
    int d = (e < N_EDGES) ? dst[e] : -1;
    dreg[k] = d;
    if (d >= 0) atomicAdd(&hist[((unsigned)d) >> BSHIFT], 1u);
  }
  __syncthreads();

  // exclusive scan of hist (thread owns buckets 4t..4t+3)
  unsigned int v[4], run = 0;
  #pragma unroll
  for (int j = 0; j < 4; ++j) {
    int bk = 4 * tid + j;
    unsigned int h = (bk < NBUCK) ? hist[bk] : 0u;
    v[j] = run;                               // local exclusive prefix
    run += h;
  }
  ts[tid] = run;
  __syncthreads();
  for (int o = 1; o < 256; o <<= 1) {
    unsigned int add = (tid >= o) ? ts[tid - o] : 0u;
    __syncthreads();
    ts[tid] += add;
    __syncthreads();
  }
  const unsigned int excl = ts[tid] - run;
  const unsigned int m = ts[255];             // real edges in this chunk
  unsigned short* trow = tbl + (size_t)blockIdx.x * TBL_STRIDE;
  #pragma unroll
  for (int j = 0; j < 4; ++j) {
    int bk = 4 * tid + j;
    if (bk < NBUCK) {
      unsigned int o = excl + v[j];
      hist[bk] = o;
      trow[bk] = (unsigned short)o;
    }
  }
  if (tid == 0) trow[NBUCK] = (unsigned short)m;
  __syncthreads();

  #pragma unroll
  for (int k = 0; k < 16; ++k) {
    int e = e0 + k * 256 + tid;
    int t = dreg[k];
    if (t >= 0) {
      unsigned int pos = atomicAdd(&hist[((unsigned)t) >> BSHIFT], 1u);
      sorted[pos] = (((unsigned)(t & (BNODES - 1))) << 17) | (unsigned)src[e];
    }
  }
  __syncthreads();

  unsigned int* so = stage + (size_t)blockIdx.x * P1_CHUNK;
  for (int i = tid; i < (int)m; i += 256) so[i] = sorted[i];
}

// ---------------------------------------------------------------------------
// Pass 2: paired-segment gather (thread owns chunk-segments 2t, 2t+1), single
// read of stage, LDS counting sort to node CSR. Emits eSrc, off, edeg, dinv,
// and the fused layer-1 prescale Xs.
// ---------------------------------------------------------------------------
__global__ __launch_bounds__(512) void pass2_sort(
    const unsigned int* __restrict__ stage, const unsigned short* __restrict__ tbl,
    int* __restrict__ eSrc, int* __restrict__ off, int* __restrict__ edeg,
    float* __restrict__ dinv, const float* __restrict__ x,
    unsigned short* __restrict__ Xs) {
  __shared__ int spre[512];
  __shared__ int cnt[BNODES];
  __shared__ int ts[BNODES];
  __shared__ float dinvL[BNODES];
  __shared__ unsigned int raw[BCAP];
  __shared__ int sorted[BCAP];
  const int b = blockIdx.x, tid = threadIdx.x;
  const int n0 = b * BNODES;

  // phase 0: my two segments' base/len; scan combined lengths
  int base0 = 0, base1 = 0, len0 = 0, len1 = 0;
  {
    int s0 = 2 * tid, s1 = 2 * tid + 1;
    if (s0 < NB_P1) {
      const unsigned short* trow = tbl + (size_t)s0 * TBL_STRIDE;
      int o0 = trow[b], o1 = trow[b + 1];
      base0 = s0 * P1_CHUNK + o0;
      len0 = o1 - o0;
    }
    if (s1 < NB_P1) {
      const unsigned short* trow = tbl + (size_t)s1 * TBL_STRIDE;
      int o0 = trow[b], o1 = trow[b + 1];
      base1 = s1 * P1_CHUNK + o0;
      len1 = o1 - o0;
    }
  }
  if (tid < BNODES) cnt[tid] = 0;
  const int mylen = len0 + len1;
  spre[tid] = mylen;
  __syncthreads();
  for (int o = 1; o < 512; o <<= 1) {
    int add = (tid >= o) ? spre[tid - o] : 0;
    __syncthreads();
    spre[tid] += add;
    __syncthreads();
  }
  const int m = spre[511];
  const int pref = spre[tid] - mylen;

  // phase A: walk my segments; gather + histogram + stash
  for (int j = 0; j < len0; ++j) {
    unsigned int p = stage[base0 + j];
    raw[pref + j] = p;
    atomicAdd(&cnt[p >> 17], 1);
  }
  for (int j = 0; j < len1; ++j) {
    unsigned int p = stage[base1 + j];
    raw[pref + len0 + j] = p;
    atomicAdd(&cnt[p >> 17], 1);
  }
  __syncthreads();

  // phase B: node scan -> off/edeg/dinv, cursors
  int v = 0;
  if (tid < BNODES) { v = cnt[tid]; ts[tid] = v; }
  __syncthreads();
  for (int o = 1; o < BNODES; o <<= 1) {
    int add = (tid >= o && tid < BNODES) ? ts[tid - o] : 0;
    __syncthreads();
    if (tid < BNODES) ts[tid] += add;
    __syncthreads();
  }
  if (tid < BNODES) {
    int excl = ts[tid] - v;
    int node = n0 + tid;
    float dv = rsqrtf((float)v + 1.0f);
    dinvL[tid] = dv;
    if (node < N_NODES) {
      off[node]  = b * BCAP + excl;
      edeg[node] = v;
      dinv[node] = dv;
    }
    cnt[tid] = excl;                          // becomes cursor
  }
  __syncthreads();

  // phase C: LDS scatter into node order
  for (int i = tid; i < m; i += 512) {
    unsigned int p = raw[i];
    int pos = atomicAdd(&cnt[p >> 17], 1);
    if (pos < BCAP) sorted[pos] = (int)(p & SRC_MASK);
  }
  __syncthreads();

  // phase D: coalesced write-out
  int* out = eSrc + (size_t)b * BCAP;
  for (int i = tid; i < m; i += 512) out[i] = sorted[i];

  // fused layer-1 prescale for this block's node range
  const int rows = min(BNODES, N_NODES - n0);
  for (int i = tid; i < rows * 64; i += 512) {
    int r = i >> 6;
    size_t g = (size_t)(n0 + r) * 64 + (i & 63);
    Xs[g] = f2bf(dinvL[r] * x[g]);
  }
}

// ---------------------------------------------------------------------------
// CSR aggregation (v3): one wave per node, 8 edges per uint4 gather, bf16 out.
// Main loop unmasked (full 32-edge batches); single masked tail batch.
// Memory-floor bound: FETCH ~160MB/layer at ~3.3 TB/s fabric (measured R10/11).
// ---------------------------------------------------------------------------
__global__ __launch_bounds__(256) void agg_csr(
    const int* __restrict__ off, const int* __restrict__ edeg,
    const int* __restrict__ eSrc, const unsigned short* __restrict__ Xs,
    const float* __restrict__ dinv, unsigned short* __restrict__ agg) {
  const int wid = (blockIdx.x * 256 + threadIdx.x) >> 6;
  const int lane = threadIdx.x & 63;
  const int grp = lane >> 3, sub = lane & 7;
  if (wid >= N_NODES) return;
  const int s0 = off[wid];
  const int s1 = s0 + edeg[wid];
  const uint4* XsV = (const uint4*)Xs;

  float2 acc[4];
  {
    uint4 u = XsV[(size_t)wid * 8 + sub];     // self loop: only grp 0 adds it
    if (grp != 0) { u.x = 0; u.y = 0; u.z = 0; u.w = 0; }
    acc[0] = bfpair(u.x);
    acc[1] = bfpair(u.y);
    acc[2] = bfpair(u.z);
    acc[3] = bfpair(u.w);
  }

  int e = s0;
  const int eend = s1 - ((s1 - s0) & 31);
  for (; e < eend; e += 32) {                 // unmasked, 4 gathers in flight
    int sa = eSrc[e + grp];
    int sb = eSrc[e + 8 + grp];
    int sc = eSrc[e + 16 + grp];
    int sd = eSrc[e + 24 + grp];
    uint4 ua = XsV[(size_t)sa * 8 + sub];
    uint4 ub = XsV[(size_t)sb * 8 + sub];
    uint4 uc = XsV[(size_t)sc * 8 + sub];
    uint4 ud = XsV[(size_t)sd * 8 + sub];
    addp(acc, ua); addp(acc, ub); addp(acc, uc); addp(acc, ud);
  }
  if (e < s1) {                               // single masked tail batch
    const int lim = s1 - 1;
    int ea = e + grp, eb = e + 8 + grp, ec = e + 16 + grp, ed = e + 24 + grp;
    int sa = eSrc[min(ea, lim)];
    int sb = eSrc[min(eb, lim)];
    int sc = eSrc[min(ec, lim)];
    int sd = eSrc[min(ed, lim)];
    uint4 ua = XsV[(size_t)sa * 8 + sub];
    uint4 ub = XsV[(size_t)sb * 8 + sub];
    uint4 uc = XsV[(size_t)sc * 8 + sub];
    uint4 ud = XsV[(size_t)sd * 8 + sub];
    if (ea > lim) { ua.x = 0; ua.y = 0; ua.z = 0; ua.w = 0; }
    if (eb > lim) { ub.x = 0; ub.y = 0; ub.z = 0; ub.w = 0; }
    if (ec > lim) { uc.x = 0; uc.y = 0; uc.z = 0; uc.w = 0; }
    if (ed > lim) { ud.x = 0; ud.y = 0; ud.z = 0; ud.w = 0; }
    addp(acc, ua); addp(acc, ub); addp(acc, uc); addp(acc, ud);
  }

  #pragma unroll
  for (int mk = 8; mk <= 32; mk <<= 1) {
    #pragma unroll
    for (int i = 0; i < 4; ++i) {
      acc[i].x += __shfl_xor(acc[i].x, mk, 64);
      acc[i].y += __shfl_xor(acc[i].y, mk, 64);
    }
  }

  if (grp == 0) {
    float dt = dinv[wid];
    uint4 o;
    o.x = ((unsigned)f2bf(acc[0].y * dt) << 16) | f2bf(acc[0].x * dt);
    o.y = ((unsigned)f2bf(acc[1].y * dt) << 16) | f2bf(acc[1].x * dt);
    o.z = ((unsigned)f2bf(acc[2].y * dt) << 16) | f2bf(acc[2].x * dt);
    o.w = ((unsigned)f2bf(acc[3].y * dt) << 16) | f2bf(acc[3].x * dt);
    *(uint4*)(agg + (size_t)wid * 64 + sub * 8) = o;
  }
}

// ---------------------------------------------------------------------------
// MFMA GEMM: Yb(bf16)[128-row block] = A(bf16) @ WcB + bc, fused col stats.
// ---------------------------------------------------------------------------
__global__ __launch_bounds__(256) void gemm_stats(
    const unsigned short* __restrict__ A, const unsigned int* __restrict__ WcB,
    const float* __restrict__ bc, unsigned short* __restrict__ Yb,
    float* __restrict__ colsum, float* __restrict__ colsq) {
  const int tid = threadIdx.x;
  const int L = tid & 63, wv = tid >> 6;
  const int quad = L >> 4, l16 = L & 15;

  const bf16x8* Wv = (const bf16x8*)WcB;
  bf16x8 bfr[4][2];
  #pragma unroll
  for (int nt = 0; nt < 4; ++nt)
    #pragma unroll
    for (int kh = 0; kh < 2; ++kh)
      bfr[nt][kh] = Wv[(nt * 2 + kh) * 64 + L];
  float bcv[4];
  #pragma unroll
  for (int nt = 0; nt < 4; ++nt) bcv[nt] = bc[nt * 16 + l16];

  const bf16x8* Av = (const bf16x8*)A;
  float psum[4] = {0.f, 0.f, 0.f, 0.f}, psq[4] = {0.f, 0.f, 0.f, 0.f};

  #pragma unroll
  for (int loop = 0; loop < 2; ++loop) {
    const int rowbase = blockIdx.x * 128 + loop * 64 + wv * 16;
    const int m = min(rowbase + l16, N_NODES - 1);
    bf16x8 a0 = Av[(size_t)m * 8 + quad];
    bf16x8 a1 = Av[(size_t)m * 8 + 4 + quad];
    #pragma unroll
    for (int nt = 0; nt < 4; ++nt) {
      f32x4 acc = {0.f, 0.f, 0.f, 0.f};
      acc = __builtin_amdgcn_mfma_f32_16x16x32_bf16(a0, bfr[nt][0], acc, 0, 0, 0);
      acc = __builtin_amdgcn_mfma_f32_16x16x32_bf16(a1, bfr[nt][1], acc, 0, 0, 0);
      #pragma unroll
      for (int r = 0; r < 4; ++r) {
        int row = rowbase + quad * 4 + r;
        if (row < N_NODES) {
          float y = acc[r] + bcv[nt];
          Yb[(size_t)row * 64 + nt * 16 + l16] = f2bf(y);
          psum[nt] += y;
          psq[nt] += y * y;
        }
      }
    }
  }

  #pragma unroll
  for (int nt = 0; nt < 4; ++nt) {
    psum[nt] += __shfl_xor(psum[nt], 16, 64);
    psum[nt] += __shfl_xor(psum[nt], 32, 64);
    psq[nt]  += __shfl_xor(psq[nt], 16, 64);
    psq[nt]  += __shfl_xor(psq[nt], 32, 64);
  }
  __shared__ float rsum[4][64];
  __shared__ float rsq[4][64];
  if (L < 16) {
    #pragma unroll
    for (int nt = 0; nt < 4; ++nt) {
      rsum[wv][nt * 16 + L] = psum[nt];
      rsq[wv][nt * 16 + L]  = psq[nt];
    }
  }
  __syncthreads();
  if (tid < 64) {
    float s = rsum[0][tid] + rsum[1][tid] + rsum[2][tid] + rsum[3][tid];
    float q = rsq[0][tid] + rsq[1][tid] + rsq[2][tid] + rsq[3][tid];
    atomicAdd(&colsum[tid], s);
    atomicAdd(&colsq[tid], q);
  }
}

// ---------------------------------------------------------------------------
// prescale_y (+inline finalize of layer-1 BN), in place over the Yb buffer
// ---------------------------------------------------------------------------
__global__ __launch_bounds__(256) void prescale_y(
    unsigned short* __restrict__ YbXs, const float* __restrict__ dinv,
    const float* __restrict__ colsum, const float* __restrict__ colsq,
    const float* __restrict__ g, const float* __restrict__ bt) {
  __shared__ float sa[64], sc[64];
  if (threadIdx.x < 64) {
    int j = threadIdx.x;
    float mu = colsum[j] * (1.0f / N_NODES);
    float var = colsq[j] * (1.0f / N_NODES) - mu * mu;
    float s = rsqrtf(var + EPS) * g[j];
    sa[j] = s;
    sc[j] = bt[j] - mu * s;
  }
  __syncthreads();
  int idx = blockIdx.x * blockDim.x + threadIdx.x;
  if (idx < N_NODES * D) {
    int i = idx >> 6, j = idx & 63;
    float y = bf2f(YbXs[idx]);
    YbXs[idx] = f2bf(dinv[i] * fmaxf(fmaf(y, sa[j], sc[j]), 0.f));
  }
}

// ---------------------------------------------------------------------------
// final_norm (+inline finalize of layer-2 BN): out = relu(Yb*a2 + c2), fp32
// ---------------------------------------------------------------------------
__global__ __launch_bounds__(256) void final_norm(
    const unsigned short* __restrict__ Yb, float* __restrict__ out,
    const float* __restrict__ colsum, const float* __restrict__ colsq,
    const float* __restrict__ g, const float* __restrict__ bt) {
  __shared__ float sa[64], sc[64];
  if (threadIdx.x < 64) {
    int j = threadIdx.x;
    float mu = colsum[j] * (1.0f / N_NODES);
    float var = colsq[j] * (1.0f / N_NODES) - mu * mu;
    float s = rsqrtf(var + EPS) * g[j];
    sa[j] = s;
    sc[j] = bt[j] - mu * s;
  }
  __syncthreads();
  int idx = blockIdx.x * blockDim.x + threadIdx.x;
  if (idx < N_NODES * D) {
    int j = idx & 63;
    out[idx] = fmaxf(fmaf(bf2f(Yb[idx]), sa[j], sc[j]), 0.f);
  }
}

extern "C" void kernel_launch(void* const* d_in, const int* in_sizes, int n_in,
                              void* d_out, int out_size, void* d_ws, size_t ws_size,
                              hipStream_t stream) {
  const float* x   = (const float*)d_in[0];
  const int*   src = (const int*)d_in[1];          // edge_index row 0
  const int*   dst = src + N_EDGES;                // edge_index row 1
  const float* W1  = (const float*)d_in[2];
  const float* b1  = (const float*)d_in[3];
  const float* fw1 = (const float*)d_in[4];
  const float* fb1 = (const float*)d_in[5];
  const float* g1  = (const float*)d_in[6];
  const float* bt1 = (const float*)d_in[7];
  const float* W2  = (const float*)d_in[8];
  const float* b2  = (const float*)d_in[9];
  const float* fw2 = (const float*)d_in[10];
  const float* fb2 = (const float*)d_in[11];
  const float* g2  = (const float*)d_in[12];
  const float* bt2 = (const float*)d_in[13];

  float* out = (float*)d_out;                      // N x 64 fp32

  // workspace (~43 MB). stage aliases aggb; XsYb doubles as the bf16 Y buffer.
  unsigned char* w = (unsigned char*)d_ws;
  unsigned int*   stage = (unsigned int*)w;              // NB_P1*4096 uints
  unsigned short* aggb  = (unsigned short*)w;            // N*64 bf16 (alias)
  size_t ofs = ((size_t)NB_P1 * P1_CHUNK * 4 + 255) & ~(size_t)255;
  float*          dinv  = (float*)(w + ofs);             // N floats
  unsigned short* XsYb  = (unsigned short*)(dinv + N_NODES);          // N*64 bf16
  int*            eSrc  = (int*)(XsYb + (size_t)N_NODES * D);         // NBUCK*BCAP ints
  int*            off   = eSrc + (size_t)NBUCK * BCAP;   // N ints
  int*            edeg  = off + N_NODES;                 // N ints
  unsigned short* tbl   = (unsigned short*)(edeg + N_NODES);          // NB_P1*784 ushort
  unsigned int* WcB1 = (unsigned int*)(tbl + (size_t)NB_P1 * TBL_STRIDE); // 2048
  float* bc1  = (float*)(WcB1 + 2048);             // 64
  unsigned int* WcB2 = (unsigned int*)(bc1 + 64);  // 2048
  float* bc2  = (float*)(WcB2 + 2048);             // 64
  float* sum1 = bc2 + 64;                          // 64  (sum1..sq2 contiguous 256)
  float* sq1  = sum1 + 64;
  float* sum2 = sq1 + 64;
  float* sq2  = sum2 + 64;

  const int nd = N_NODES * D;
  dim3 blk(256);

  combine_weights<<<3, blk, 0, stream>>>(W1, b1, fw1, fb1, W2, b2, fw2, fb2,
                                         WcB1, bc1, WcB2, bc2, sum1);

  // ---- partition: block-local sort -> per-bucket node CSR (+L1 prescale) ----
  pass1_sort<<<NB_P1, blk, 0, stream>>>(src, dst, stage, tbl);
  pass2_sort<<<NBUCK, 512, 0, stream>>>(stage, tbl, eSrc, off, edeg, dinv, x, XsYb);

  // ---- layer 1 ----
  agg_csr<<<(nd + 255) / 256, blk, 0, stream>>>(off, edeg, eSrc, XsYb, dinv, aggb);
  gemm_stats<<<(N_NODES + 127) / 128, blk, 0, stream>>>(aggb, WcB1, bc1, XsYb, sum1, sq1);

  // ---- layer 2 ----
  prescale_y<<<(nd + 255) / 256, blk, 0, stream>>>(XsYb, dinv, sum1, sq1, g1, bt1);
  agg_csr<<<(nd + 255) / 256, blk, 0, stream>>>(off, edeg, eSrc, XsYb, dinv, aggb);
  gemm_stats<<<(N_NODES + 127) / 128, blk, 0, stream>>>(aggb, WcB2, bc2, XsYb, sum2, sq2);

  final_norm<<<(nd + 255) / 256, blk, 0, stream>>>(XsYb, out, sum2, sq2, g2, bt2);
}